// Round 1
// baseline (628.047 us; speedup 1.0000x reference)
//
#include <hip/hip_runtime.h>
#include <stdint.h>

typedef unsigned short u16;
typedef unsigned int u32;
typedef short shortx8 __attribute__((ext_vector_type(8)));
typedef float floatx4 __attribute__((ext_vector_type(4)));

__device__ __forceinline__ u16 f2bf(float f) {
    u32 u = __builtin_bit_cast(u32, f);
    u = (u + 0x7fffu + ((u >> 16) & 1u)) >> 16;
    return (u16)u;
}
__device__ __forceinline__ float bf2f(u16 h) {
    return __builtin_bit_cast(float, (u32)h << 16);
}

#if defined(__has_builtin)
#  if __has_builtin(__builtin_amdgcn_global_load_lds)
#    define HAVE_GLL 1
#  endif
#endif
#ifndef HAVE_GLL
#  define HAVE_GLL 0
#endif

#if HAVE_GLL
__device__ __forceinline__ void gload_lds16(const u16* g, u16* l) {
    __builtin_amdgcn_global_load_lds(
        (const __attribute__((address_space(1))) u32*)(const void*)g,
        (__attribute__((address_space(3))) u32*)(void*)l,
        16, 0, 0);
}
#endif

// ---------------------------------------------------------------------------
// GEMM: C[m,n] = sum_k A[m,k] * Bt[n,k]  (+ epilogue per MODE)
// A: (M,K) bf16 row-major lda; Bt: (N,K) bf16 row-major ldb.
// 128x128 tile, BK=32, 256 threads = 4 waves in 2x2, each wave 64x64 via
// 4x4 MFMA 16x16x32 tiles. Single-buffered LDS, global_load_lds width 16.
// MODE: 1 = +colbias aux[n]; 2 = +rowbias aux[m]; 3 = exp(acc*scale);
//       4 = acc * aux[m] (row scale)
// ---------------------------------------------------------------------------
template <typename OutT, int MODE>
__global__ __launch_bounds__(256, 2) void gemm_bt(
    const u16* __restrict__ Ag, const u16* __restrict__ Bg, OutT* __restrict__ Cg,
    int lda, int ldb, int ldc, int K,
    const float* __restrict__ aux, float scale,
    long long sAz, long long sBz, long long sCz, long long sXz)
{
    __shared__ u16 As[128 * 32];
    __shared__ u16 Bs[128 * 32];

    const u16* A = Ag + (long long)blockIdx.z * sAz;
    const u16* B = Bg + (long long)blockIdx.z * sBz;
    OutT* C = Cg + (long long)blockIdx.z * sCz;
    const float* auxp = nullptr;
    if constexpr (MODE == 1 || MODE == 2 || MODE == 4)
        auxp = aux + (long long)blockIdx.z * sXz;

    const int m0 = blockIdx.y * 128, n0 = blockIdx.x * 128;
    const int tid = threadIdx.x, lane = tid & 63, wv = tid >> 6;

    // staging: issue i covers rows [i*64, i*64+64); wave wv handles 16 rows.
    const int srow = lane >> 2;        // 0..15
    const int schunk = (lane & 3) * 8; // element offset of this lane's 16B
    const u16* gA0 = A + (size_t)(m0 + wv * 16 + srow) * lda + schunk;
    const u16* gA1 = gA0 + (size_t)64 * lda;
    const u16* gB0 = B + (size_t)(n0 + wv * 16 + srow) * ldb + schunk;
    const u16* gB1 = gB0 + (size_t)64 * ldb;
    u16* lA0 = As + wv * 512;          // wave-uniform LDS bases (bytes wv*1024)
    u16* lA1 = As + 2048 + wv * 512;
    u16* lB0 = Bs + wv * 512;
    u16* lB1 = Bs + 2048 + wv * 512;

    const int wm = (wv & 1) * 64, wn = (wv >> 1) * 64;
    const int mi = lane & 15, kq = lane >> 4;

    floatx4 acc[4][4] = {};

    for (int k0 = 0; k0 < K; k0 += 32) {
#if HAVE_GLL
        gload_lds16(gA0, lA0);
        gload_lds16(gA1, lA1);
        gload_lds16(gB0, lB0);
        gload_lds16(gB1, lB1);
#else
        *(shortx8*)(lA0 + lane * 8) = *(const shortx8*)gA0;
        *(shortx8*)(lA1 + lane * 8) = *(const shortx8*)gA1;
        *(shortx8*)(lB0 + lane * 8) = *(const shortx8*)gB0;
        *(shortx8*)(lB1 + lane * 8) = *(const shortx8*)gB1;
#endif
        gA0 += 32; gA1 += 32; gB0 += 32; gB1 += 32;
        __syncthreads();

        shortx8 af[4], bfr[4];
#pragma unroll
        for (int i = 0; i < 4; i++)
            af[i] = *(const shortx8*)(As + (wm + i * 16 + mi) * 32 + kq * 8);
#pragma unroll
        for (int j = 0; j < 4; j++)
            bfr[j] = *(const shortx8*)(Bs + (wn + j * 16 + mi) * 32 + kq * 8);
#pragma unroll
        for (int i = 0; i < 4; i++)
#pragma unroll
            for (int j = 0; j < 4; j++)
                acc[i][j] = __builtin_amdgcn_mfma_f32_16x16x32_bf16(
                    af[i], bfr[j], acc[i][j], 0, 0, 0);
        __syncthreads();
    }

    // epilogue. C/D layout: col = lane&15, row = (lane>>4)*4 + reg.
    float cb[4];
    if constexpr (MODE == 1) {
#pragma unroll
        for (int j = 0; j < 4; j++) cb[j] = auxp[n0 + wn + j * 16 + mi];
    }
#pragma unroll
    for (int i = 0; i < 4; i++) {
#pragma unroll
        for (int r = 0; r < 4; r++) {
            const int row = m0 + wm + i * 16 + kq * 4 + r;
            float radd = 0.f, rmul = 1.f;
            if constexpr (MODE == 2) radd = auxp[row];
            if constexpr (MODE == 4) rmul = auxp[row];
            OutT* crow = C + (size_t)row * ldc;
#pragma unroll
            for (int j = 0; j < 4; j++) {
                const int col = n0 + wn + j * 16 + mi;
                float v = acc[i][j][r];
                if constexpr (MODE == 1) v += cb[j];
                if constexpr (MODE == 2) v += radd;
                if constexpr (MODE == 3) v = __expf(v * scale);
                if constexpr (MODE == 4) v *= rmul;
                if constexpr (sizeof(OutT) == 2) crow[col] = f2bf(v);
                else                             crow[col] = v;
            }
        }
    }
}

// fp32 -> bf16, 8 elements per thread
__global__ __launch_bounds__(256) void cvt_bf16(const float* __restrict__ s,
                                                u16* __restrict__ d, int n8)
{
    int i = blockIdx.x * 256 + threadIdx.x;
    if (i >= n8) return;
    const float4* sp = (const float4*)s;
    float4 a = sp[2 * i], b = sp[2 * i + 1];
    uint4 o;
    o.x = (u32)f2bf(a.x) | ((u32)f2bf(a.y) << 16);
    o.y = (u32)f2bf(a.z) | ((u32)f2bf(a.w) << 16);
    o.z = (u32)f2bf(b.x) | ((u32)f2bf(b.y) << 16);
    o.w = (u32)f2bf(b.z) | ((u32)f2bf(b.w) << 16);
    *(uint4*)(d + 8 * i) = o;
}

__global__ void concat2(const float* __restrict__ a, const float* __restrict__ b,
                        float* __restrict__ d, int n)
{
    int i = blockIdx.x * 256 + threadIdx.x;
    if (i < n) d[i] = a[i];
    else if (i < 2 * n) d[i] = b[i - n];
}

// linv[row] = 1 / sum_j P[row, j]
__global__ __launch_bounds__(256) void rowsum_inv(const u16* __restrict__ P,
                                                  float* __restrict__ linv, int rowlen)
{
    __shared__ float wsum[4];
    const int row = blockIdx.x;
    const u16* p = P + (size_t)row * rowlen;
    float s = 0.f;
    for (int i = threadIdx.x * 8; i < rowlen; i += 256 * 8) {
        shortx8 v = *(const shortx8*)(p + i);
#pragma unroll
        for (int j = 0; j < 8; j++) s += bf2f((u16)v[j]);
    }
    for (int o = 32; o > 0; o >>= 1) s += __shfl_down(s, o);
    if ((threadIdx.x & 63) == 0) wsum[threadIdx.x >> 6] = s;
    __syncthreads();
    if (threadIdx.x == 0)
        linv[row] = 1.0f / (wsum[0] + wsum[1] + wsum[2] + wsum[3]);
}

extern "C" void kernel_launch(void* const* d_in, const int* in_sizes, int n_in,
                              void* d_out, int out_size, void* d_ws, size_t ws_size,
                              hipStream_t stream)
{
    const float* X  = (const float*)d_in[0];
    const float* Wq = (const float*)d_in[1];
    const float* bq = (const float*)d_in[2];
    const float* Wk = (const float*)d_in[3];
    const float* bk = (const float*)d_in[4];
    const float* Wv = (const float*)d_in[5];
    const float* bv = (const float*)d_in[6];
    float* out = (float*)d_out;

    const int T = 4096, NT = 4 * T; // 16384 tokens

    char* ws = (char*)d_ws;
    size_t off = 0;
    auto alloc = [&](size_t bytes) {
        char* p = ws + off;
        off += (bytes + 255) & ~(size_t)255;
        return p;
    };
    u16*   Wqk  = (u16*)alloc((size_t)2048 * 1024 * 2);
    u16*   Wvb  = (u16*)alloc((size_t)1024 * 1024 * 2);
    float* bqk  = (float*)alloc(2048 * 4);
    u16*   QK   = (u16*)alloc((size_t)NT * 2048 * 2);     // [token][q(1024)|k(1024)]
    u16*   Vt   = (u16*)alloc((size_t)1024 * NT * 2);     // V^T: [v][token]
    float* linv = (float*)alloc((size_t)NT * 4);
    size_t pbase = off;
    u16*   Xb   = (u16*)alloc((size_t)NT * 1024 * 2);     // X bf16; later reused as P
    u16*   P    = Xb;

    const size_t need_batched = pbase + (size_t)4 * T * T * 2;
    const bool batched = ws_size >= need_batched;

    // --- convert inputs to bf16 ---
    cvt_bf16<<<dim3((NT * 1024 / 8 + 255) / 256), dim3(256), 0, stream>>>(X, Xb, NT * 1024 / 8);
    cvt_bf16<<<dim3(512), dim3(256), 0, stream>>>(Wq, Wqk, 1024 * 1024 / 8);
    cvt_bf16<<<dim3(512), dim3(256), 0, stream>>>(Wk, Wqk + 1024 * 1024, 1024 * 1024 / 8);
    cvt_bf16<<<dim3(512), dim3(256), 0, stream>>>(Wv, Wvb, 1024 * 1024 / 8);
    concat2<<<dim3(8), dim3(256), 0, stream>>>(bq, bk, bqk, 1024);

    // --- QK = X * [Wq;Wk]^T + bqk : M=16384, N=2048, K=1024, col-bias ---
    gemm_bt<u16, 1><<<dim3(2048 / 128, NT / 128, 1), dim3(256), 0, stream>>>(
        Xb, Wqk, QK, 1024, 1024, 2048, 1024, bqk, 0.f, 0, 0, 0, 0);

    // --- V^T = Wv * X^T + bv(row) : M=1024, N=16384, K=1024, row-bias ---
    gemm_bt<u16, 2><<<dim3(NT / 128, 1024 / 128, 1), dim3(256), 0, stream>>>(
        Wvb, Xb, Vt, 1024, 1024, NT, 1024, bv, 0.f, 0, 0, 0, 0);

    if (batched) {
        // P~ = exp(Q K^T / 32), all 4 batches
        gemm_bt<u16, 3><<<dim3(T / 128, T / 128, 4), dim3(256), 0, stream>>>(
            QK, QK + 1024, P, 2048, 2048, T, 1024, nullptr, 0.03125f,
            (long long)T * 2048, (long long)T * 2048, (long long)T * T, 0);
        rowsum_inv<<<dim3(NT), dim3(256), 0, stream>>>(P, linv, T);
        // out = (P~ * V) * linv
        gemm_bt<float, 4><<<dim3(1024 / 128, T / 128, 4), dim3(256), 0, stream>>>(
            P, Vt, out, T, NT, 1024, T, linv, 0.f,
            (long long)T * T, (long long)T, (long long)T * 1024, (long long)T);
    } else {
        for (int z = 0; z < 4; z++) {
            const u16* Qz = QK + (size_t)z * T * 2048;
            gemm_bt<u16, 3><<<dim3(T / 128, T / 128, 1), dim3(256), 0, stream>>>(
                Qz, Qz + 1024, P, 2048, 2048, T, 1024, nullptr, 0.03125f, 0, 0, 0, 0);
            rowsum_inv<<<dim3(T), dim3(256), 0, stream>>>(P, linv + (size_t)z * T, T);
            gemm_bt<float, 4><<<dim3(1024 / 128, T / 128, 1), dim3(256), 0, stream>>>(
                P, Vt + (size_t)z * T, out + (size_t)z * T * 1024,
                T, NT, 1024, T, linv + (size_t)z * T, 0.f, 0, 0, 0, 0);
        }
    }
    (void)in_sizes; (void)n_in; (void)out_size;
}

// Round 2
// 582.485 us; speedup vs baseline: 1.0782x; 1.0782x over previous
//
#include <hip/hip_runtime.h>
#include <stdint.h>

typedef unsigned short u16;
typedef unsigned int u32;
typedef short shortx8 __attribute__((ext_vector_type(8)));
typedef float floatx4 __attribute__((ext_vector_type(4)));

__device__ __forceinline__ u16 f2bf(float f) {
    u32 u = __builtin_bit_cast(u32, f);
    u = (u + 0x7fffu + ((u >> 16) & 1u)) >> 16;
    return (u16)u;
}
__device__ __forceinline__ float bf2f(u16 h) {
    return __builtin_bit_cast(float, (u32)h << 16);
}

#if defined(__has_builtin)
#  if __has_builtin(__builtin_amdgcn_global_load_lds)
#    define HAVE_GLL 1
#  endif
#endif
#ifndef HAVE_GLL
#  define HAVE_GLL 0
#endif

#if HAVE_GLL
__device__ __forceinline__ void gload_lds16(const u16* g, u16* l) {
    __builtin_amdgcn_global_load_lds(
        (const __attribute__((address_space(1))) u32*)(const void*)g,
        (__attribute__((address_space(3))) u32*)(void*)l,
        16, 0, 0);
}
#endif

// ---------------------------------------------------------------------------
// GEMM: C[m,n] = sum_k A[m,k] * Bt[n,k]  (+ epilogue per MODE)
// A: (M,K) bf16 row-major lda; Bt: (N,K) bf16 row-major ldb. K % 64 == 0.
// 128x128 tile, BK=64 as two BK=32 panels per barrier (32 MFMA/barrier),
// 256 threads = 4 waves in 2x2, each wave 64x64 via 4x4 16x16x32 MFMA.
// bf16 outputs go through an LDS-staged coalesced store (reuses K-loop LDS).
// MODE: 1 = +colbias aux[n]; 2 = +rowbias aux[m];
//       3 = exp(acc*scale), fused row-sum atomicAdd into sums[m];
//       4 = acc / aux[m]  (fp32 out)
// SWZ=1: 1D grid, f&7 -> XCD slot: z = xcd>>1, n-half = xcd&1 (batch pinned
//        to an XCD pair for L2/LLC locality). Requires 32 m-blocks.
// ---------------------------------------------------------------------------
template <typename OutT, int MODE, int SWZ>
__global__ __launch_bounds__(256, 2) void gemm_bt(
    const u16* __restrict__ Ag, const u16* __restrict__ Bg, OutT* __restrict__ Cg,
    int lda, int ldb, int ldc, int K,
    const float* __restrict__ aux, float* __restrict__ sums, float scale,
    long long sAz, long long sBz, long long sCz, long long sXz,
    int swz_nhalf)
{
    __shared__ u16 smem[4][128 * 32];   // 32 KB: A panels 0/1, B panels 0/1

    int z, mb, nb;
    if constexpr (SWZ) {
        const int f = blockIdx.x, xcd = f & 7, g = f >> 3;
        z = xcd >> 1;
        mb = g & 31;
        nb = (xcd & 1) * swz_nhalf + (g >> 5);
    } else {
        z = blockIdx.z; mb = blockIdx.y; nb = blockIdx.x;
    }
    const int m0 = mb * 128, n0 = nb * 128;

    const u16* A = Ag + (long long)z * sAz;
    const u16* B = Bg + (long long)z * sBz;
    OutT* C = Cg + (long long)z * sCz;
    const float* auxp = nullptr;
    if constexpr (MODE == 1 || MODE == 2 || MODE == 4)
        auxp = aux + (long long)z * sXz;
    float* sumz = nullptr;
    if constexpr (MODE == 3) sumz = sums + (long long)z * sXz;

    const int tid = threadIdx.x, lane = tid & 63, wv = tid >> 6;

    // staging: each wave's gload covers 16 rows (1 KB) per issue.
    const int srow = lane >> 2;        // 0..15
    const int schunk = (lane & 3) * 8; // element offset of this lane's 16B
    const u16* gA0 = A + (size_t)(m0 + wv * 16 + srow) * lda + schunk;
    const u16* gA1 = gA0 + (size_t)64 * lda;
    const u16* gB0 = B + (size_t)(n0 + wv * 16 + srow) * ldb + schunk;
    const u16* gB1 = gB0 + (size_t)64 * ldb;
    const int wb = wv * 512;           // wave-uniform LDS base (u16 elems)

    const int wm = (wv & 1) * 64, wn = (wv >> 1) * 64;
    const int mi = lane & 15, kq = lane >> 4;

    floatx4 acc[4][4] = {};

    for (int k0 = 0; k0 < K; k0 += 64) {
#if HAVE_GLL
        gload_lds16(gA0,      &smem[0][wb]);
        gload_lds16(gA1,      &smem[0][2048 + wb]);
        gload_lds16(gA0 + 32, &smem[1][wb]);
        gload_lds16(gA1 + 32, &smem[1][2048 + wb]);
        gload_lds16(gB0,      &smem[2][wb]);
        gload_lds16(gB1,      &smem[2][2048 + wb]);
        gload_lds16(gB0 + 32, &smem[3][wb]);
        gload_lds16(gB1 + 32, &smem[3][2048 + wb]);
#else
        *(shortx8*)(&smem[0][wb] + lane * 8)        = *(const shortx8*)gA0;
        *(shortx8*)(&smem[0][2048 + wb] + lane * 8) = *(const shortx8*)gA1;
        *(shortx8*)(&smem[1][wb] + lane * 8)        = *(const shortx8*)(gA0 + 32);
        *(shortx8*)(&smem[1][2048 + wb] + lane * 8) = *(const shortx8*)(gA1 + 32);
        *(shortx8*)(&smem[2][wb] + lane * 8)        = *(const shortx8*)gB0;
        *(shortx8*)(&smem[2][2048 + wb] + lane * 8) = *(const shortx8*)gB1;
        *(shortx8*)(&smem[3][wb] + lane * 8)        = *(const shortx8*)(gB0 + 32);
        *(shortx8*)(&smem[3][2048 + wb] + lane * 8) = *(const shortx8*)(gB1 + 32);
#endif
        gA0 += 64; gA1 += 64; gB0 += 64; gB1 += 64;
        __syncthreads();

#pragma unroll
        for (int h = 0; h < 2; h++) {
            const u16* Ap = smem[h];
            const u16* Bp = smem[2 + h];
            shortx8 af[4], bfr[4];
#pragma unroll
            for (int i = 0; i < 4; i++)
                af[i] = *(const shortx8*)(Ap + (wm + i * 16 + mi) * 32 + kq * 8);
#pragma unroll
            for (int j = 0; j < 4; j++)
                bfr[j] = *(const shortx8*)(Bp + (wn + j * 16 + mi) * 32 + kq * 8);
#pragma unroll
            for (int i = 0; i < 4; i++)
#pragma unroll
                for (int j = 0; j < 4; j++)
                    acc[i][j] = __builtin_amdgcn_mfma_f32_16x16x32_bf16(
                        af[i], bfr[j], acc[i][j], 0, 0, 0);
        }
        __syncthreads();
    }

    // epilogue. C/D layout: col = lane&15, row = (lane>>4)*4 + reg.
    float cb[4];
    if constexpr (MODE == 1) {
#pragma unroll
        for (int j = 0; j < 4; j++) cb[j] = auxp[n0 + wn + j * 16 + mi];
    }

    if constexpr (sizeof(OutT) == 2) {
        // stage bf16 tile in LDS (reuse the 32 KB K-loop panels), then
        // fully-coalesced dwordx4 stores.
        u16* ct = &smem[0][0];
#pragma unroll
        for (int i = 0; i < 4; i++) {
#pragma unroll
            for (int r = 0; r < 4; r++) {
                const int lrow = wm + i * 16 + kq * 4 + r;
                float radd = 0.f;
                if constexpr (MODE == 2) radd = auxp[m0 + lrow];
                float rs = 0.f;
#pragma unroll
                for (int j = 0; j < 4; j++) {
                    float v = acc[i][j][r];
                    if constexpr (MODE == 1) v += cb[j];
                    if constexpr (MODE == 2) v += radd;
                    if constexpr (MODE == 3) { v = __expf(v * scale); rs += v; }
                    ct[lrow * 128 + wn + j * 16 + mi] = f2bf(v);
                }
                if constexpr (MODE == 3) {
                    // reduce over the wave's 64 cols (16 mi-lanes x 4 j)
                    rs += __shfl_xor(rs, 1);
                    rs += __shfl_xor(rs, 2);
                    rs += __shfl_xor(rs, 4);
                    rs += __shfl_xor(rs, 8);
                    if (mi == 0) atomicAdd(&sumz[m0 + lrow], rs);
                }
            }
        }
        __syncthreads();
#pragma unroll
        for (int it = 0; it < 8; it++) {
            const int fl = (it * 256 + tid) * 8;        // u16 elems, 16B chunks
            const int row = fl >> 7, col = fl & 127;
            *(uint4*)(C + (size_t)(m0 + row) * ldc + n0 + col) =
                *(const uint4*)(ct + fl);
        }
    } else {
        // fp32 direct stores (MODE 4)
#pragma unroll
        for (int i = 0; i < 4; i++) {
#pragma unroll
            for (int r = 0; r < 4; r++) {
                const int row = m0 + wm + i * 16 + kq * 4 + r;
                float rmul = 1.f;
                if constexpr (MODE == 4) rmul = 1.0f / auxp[row];
                OutT* crow = C + (size_t)row * ldc;
#pragma unroll
                for (int j = 0; j < 4; j++) {
                    const int col = n0 + wn + j * 16 + mi;
                    crow[col] = acc[i][j][r] * rmul;
                }
            }
        }
    }
}

// fp32 -> bf16, 8 elements per thread
__global__ __launch_bounds__(256) void cvt_bf16(const float* __restrict__ s,
                                                u16* __restrict__ d, int n8)
{
    int i = blockIdx.x * 256 + threadIdx.x;
    if (i >= n8) return;
    const float4* sp = (const float4*)s;
    float4 a = sp[2 * i], b = sp[2 * i + 1];
    uint4 o;
    o.x = (u32)f2bf(a.x) | ((u32)f2bf(a.y) << 16);
    o.y = (u32)f2bf(a.z) | ((u32)f2bf(a.w) << 16);
    o.z = (u32)f2bf(b.x) | ((u32)f2bf(b.y) << 16);
    o.w = (u32)f2bf(b.z) | ((u32)f2bf(b.w) << 16);
    *(uint4*)(d + 8 * i) = o;
}

__global__ void concat2(const float* __restrict__ a, const float* __restrict__ b,
                        float* __restrict__ d, int n)
{
    int i = blockIdx.x * 256 + threadIdx.x;
    if (i < n) d[i] = a[i];
    else if (i < 2 * n) d[i] = b[i - n];
}

extern "C" void kernel_launch(void* const* d_in, const int* in_sizes, int n_in,
                              void* d_out, int out_size, void* d_ws, size_t ws_size,
                              hipStream_t stream)
{
    const float* X  = (const float*)d_in[0];
    const float* Wq = (const float*)d_in[1];
    const float* bq = (const float*)d_in[2];
    const float* Wk = (const float*)d_in[3];
    const float* bk = (const float*)d_in[4];
    const float* Wv = (const float*)d_in[5];
    const float* bv = (const float*)d_in[6];
    float* out = (float*)d_out;

    const int T = 4096, NT = 4 * T; // 16384 tokens
    const long long TL = T;

    char* ws = (char*)d_ws;
    size_t off = 0;
    auto alloc = [&](size_t bytes) {
        char* p = ws + off;
        off += (bytes + 255) & ~(size_t)255;
        return p;
    };
    u16*   Wqk  = (u16*)alloc((size_t)2048 * 1024 * 2);
    u16*   Wvb  = (u16*)alloc((size_t)1024 * 1024 * 2);
    float* bqk  = (float*)alloc(2048 * 4);
    u16*   QK   = (u16*)alloc((size_t)NT * 2048 * 2);     // [token][q(1024)|k(1024)]
    u16*   Vt   = (u16*)alloc((size_t)1024 * NT * 2);     // V^T: [v][token]
    float* sums = (float*)alloc((size_t)NT * 4);          // softmax denominators
    size_t pbase = off;
    u16*   Xb   = (u16*)alloc((size_t)NT * 1024 * 2);     // X bf16; later reused as P
    u16*   P    = Xb;

    const size_t need_batched = pbase + (size_t)4 * T * T * 2;
    const bool batched = ws_size >= need_batched;

    // --- convert inputs to bf16 ---
    cvt_bf16<<<dim3((NT * 1024 / 8 + 255) / 256), dim3(256), 0, stream>>>(X, Xb, NT * 1024 / 8);
    cvt_bf16<<<dim3(512), dim3(256), 0, stream>>>(Wq, Wqk, 1024 * 1024 / 8);
    cvt_bf16<<<dim3(512), dim3(256), 0, stream>>>(Wk, Wqk + 1024 * 1024, 1024 * 1024 / 8);
    cvt_bf16<<<dim3(512), dim3(256), 0, stream>>>(Wv, Wvb, 1024 * 1024 / 8);
    concat2<<<dim3(8), dim3(256), 0, stream>>>(bq, bk, bqk, 1024);
    hipMemsetAsync(sums, 0, (size_t)NT * 4, stream);

    // --- QK = X * [Wq;Wk]^T + bqk : M=16384, N=2048, K=1024, col-bias ---
    gemm_bt<u16, 1, 0><<<dim3(16, 128, 1), dim3(256), 0, stream>>>(
        Xb, Wqk, QK, 1024, 1024, 2048, 1024, bqk, nullptr, 0.f, 0, 0, 0, 0, 0);

    // --- V^T = Wv * X^T + bv(row) : M=1024, N=16384, K=1024, row-bias ---
    gemm_bt<u16, 2, 0><<<dim3(128, 8, 1), dim3(256), 0, stream>>>(
        Wvb, Xb, Vt, 1024, 1024, NT, 1024, bv, nullptr, 0.f, 0, 0, 0, 0, 0);

    if (batched) {
        // P~ = exp(Q K^T / 32) with fused row-sums; XCD-swizzled (32 m-blk, 32 n-blk, z=4)
        gemm_bt<u16, 3, 1><<<dim3(4096), dim3(256), 0, stream>>>(
            QK, QK + 1024, P, 2048, 2048, T, 1024, nullptr, sums, 0.03125f,
            TL * 2048, TL * 2048, TL * T, TL, 16);
        // out = (P~ * V) / sums ; XCD-swizzled (32 m-blk, 8 n-blk, z=4)
        gemm_bt<float, 4, 1><<<dim3(1024), dim3(256), 0, stream>>>(
            P, Vt, out, T, NT, 1024, T, sums, nullptr, 0.f,
            TL * T, TL, TL * 1024, TL, 4);
    } else {
        for (int z = 0; z < 4; z++) {
            const u16* Qz = QK + (size_t)z * T * 2048;
            gemm_bt<u16, 3, 0><<<dim3(32, 32, 1), dim3(256), 0, stream>>>(
                Qz, Qz + 1024, P, 2048, 2048, T, 1024, nullptr, sums + (size_t)z * T,
                0.03125f, 0, 0, 0, 0, 0);
            gemm_bt<float, 4, 0><<<dim3(8, 32, 1), dim3(256), 0, stream>>>(
                P, Vt + (size_t)z * T, out + (size_t)z * T * 1024,
                T, NT, 1024, T, sums + (size_t)z * T, nullptr, 0.f, 0, 0, 0, 0, 0);
        }
    }
    (void)in_sizes; (void)n_in; (void)out_size;
}